// Round 10
// baseline (96.084 us; speedup 1.0000x reference)
//
#include <hip/hip_runtime.h>

#define BTOT 65536
#define TST  28
#define PACK_DW 60
// ws layout (dwords): [0 .. 15360) packed frags (4 p-variants x 64 lanes x 60)
//                     [15360 .. 19456) WxL: 32 x 128 f32 (rows 29..31 zeroed)
#define WXL_OFF 15360

typedef __attribute__((ext_vector_type(8))) short bf16x8;
typedef __attribute__((ext_vector_type(4))) float f32x4;
typedef __attribute__((ext_vector_type(2))) unsigned int u32x2;

__device__ __forceinline__ unsigned int f2bf(float f) {
    unsigned u = __float_as_uint(f);
    u += 0x7fff + ((u >> 16) & 1);   // RNE
    return u >> 16;
}
__device__ __forceinline__ unsigned int pk2bf(float a, float b) {
    return f2bf(a) | (f2bf(b) << 16);
}
__device__ __forceinline__ bf16x8 cvt8(f32x4 a, f32x4 b) {
    union { unsigned int u[4]; bf16x8 v; } r;
    asm("v_cvt_pk_bf16_f32 %0, %1, %2" : "=v"(r.u[0]) : "v"(a[0]), "v"(a[1]));
    asm("v_cvt_pk_bf16_f32 %0, %1, %2" : "=v"(r.u[1]) : "v"(a[2]), "v"(a[3]));
    asm("v_cvt_pk_bf16_f32 %0, %1, %2" : "=v"(r.u[2]) : "v"(b[0]), "v"(b[1]));
    asm("v_cvt_pk_bf16_f32 %0, %1, %2" : "=v"(r.u[3]) : "v"(b[2]), "v"(b[3]));
    return r.v;
}

// pack1: blocks 0..28 compute WxL row k (Wx = W1@W2a; row 28 = b2 + b1@W2a, the
// bias row hit by x-frag element k=28 := 1.0; block 28 also zeroes rows 29..31).
// Block 29 packs W2b A-frags (all 4 p-quarters); block 30 packs W3 frags + b3
// (p=0 rows only — the epilogue wave).
__global__ void pack1(const float* __restrict__ W1, const float* __restrict__ b1,
                      const float* __restrict__ W2, const float* __restrict__ b2,
                      const float* __restrict__ W3, const float* __restrict__ b3,
                      unsigned int* __restrict__ ws) {
    float* WxL = (float*)(ws + WXL_OFF);
    const int bid = blockIdx.x, tid = threadIdx.x;
    if (bid < 29) {
        const int k = bid, n = tid;   // 128 threads
        float s = 0.f;
        if (k < 28) {
            for (int m = 0; m < 128; ++m) s += W1[k * 128 + m] * W2[m * 128 + n];
        } else {
            s = b2[n];
            for (int m = 0; m < 128; ++m) s += b1[m] * W2[m * 128 + n];
        }
        WxL[k * 128 + n] = s;
        if (k == 28) { WxL[29*128+n] = 0.f; WxL[30*128+n] = 0.f; WxL[31*128+n] = 0.f; }
    } else if (bid == 29) {
        if (tid < 64) {
            const int lr = tid & 15, kh = tid >> 4;
            for (int p = 0; p < 4; ++p) {
                unsigned int* P = ws + (p * 64 + tid) * PACK_DW;
                for (int kk = 0; kk < 4; ++kk)
                    for (int t4 = 0; t4 < 2; ++t4)
                        for (int jd = 0; jd < 4; ++jd) {
                            const int k = 128 + kk * 32 + kh * 8 + jd * 2;
                            const int n = p * 32 + t4 * 16 + lr;
                            P[(kk * 2 + t4) * 4 + jd] =
                                pk2bf(W2[k * 128 + n], W2[(k + 1) * 128 + n]);
                        }
            }
        }
    } else {
        if (tid < 64) {
            const int lr = tid & 15, kh = tid >> 4;
            unsigned int* P = ws + tid * PACK_DW;   // p=0 rows only
            for (int kk = 0; kk < 4; ++kk)
                for (int jd = 0; jd < 4; ++jd) {
                    const int k = kk * 32 + kh * 8 + jd * 2;
                    float lo = (lr < 10) ? W3[k * 10 + lr] : 0.f;
                    float hi = (lr < 10) ? W3[(k + 1) * 10 + lr] : 0.f;
                    P[40 + kk * 4 + jd] = pk2bf(lo, hi);
                }
            for (int j = 0; j < 4; ++j) {
                const int o = kh * 4 + j;
                P[56 + j] = __float_as_uint((o < 10) ? b3[o] : 0.f);
            }
        }
    }
}

// pack2: Wx A-frags (needs WxL from pack1's blocks 0..28).
__global__ void pack2(unsigned int* __restrict__ ws) {
    const int tid = threadIdx.x;
    if (tid < 64) {
        const float* WxL = (const float*)(ws + WXL_OFF);
        const int lr = tid & 15, kh = tid >> 4;
        for (int p = 0; p < 4; ++p) {
            unsigned int* P = ws + (p * 64 + tid) * PACK_DW;
            for (int t4 = 0; t4 < 2; ++t4)
                for (int jd = 0; jd < 4; ++jd) {
                    const int k = kh * 8 + jd * 2, n = p * 32 + t4 * 16 + lr;
                    P[32 + t4 * 4 + jd] = pk2bf(WxL[k * 128 + n], WxL[(k + 1) * 128 + n]);
                }
        }
    }
}

// Block = 4 waves = 1 team owning 16 batch rows; wave p owns n-quarter
// [32p,32p+32). W2b quarter = 32 VGPR/wave -> total regs <= 128 ->
// 4 waves/SIMD (2x the streams of rounds 6-9, which were register-capped
// at 2/SIMD with AGPRs counted). H double-buffered in LDS, 1 barrier/step.
__global__ __launch_bounds__(256, 4) void rnn_kernel(
    const float* __restrict__ x, const unsigned int* __restrict__ wsPack,
    float* __restrict__ out)
{
    __shared__ __align__(16) short Hs[2][16][136];  // [buf][batch][n + pad]
    const int tid = threadIdx.x;
    const int p = tid >> 6, lane = tid & 63, lr = lane & 15, kh = lane >> 4;
    const int r0 = blockIdx.x * 16;

    const unsigned int* P = wsPack + (p * 64 + lane) * PACK_DW;
    bf16x8 w2b[4][2], wx[2];
    #pragma unroll
    for (int kk = 0; kk < 4; ++kk)
        #pragma unroll
        for (int t4 = 0; t4 < 2; ++t4)
            w2b[kk][t4] = *(const bf16x8*)(P + (kk * 2 + t4) * 4);
    #pragma unroll
    for (int t4 = 0; t4 < 2; ++t4) wx[t4] = *(const bf16x8*)(P + 32 + t4 * 4);

    // zero both buffers: 2176 dwords / 256 threads
    unsigned int* hz = (unsigned int*)&Hs[0][0][0];
    #pragma unroll
    for (int i = 0; i < 9; ++i) {
        const int idx = tid + i * 256;
        if (idx < 2176) hz[idx] = 0u;
    }
    __syncthreads();

    // x B-frag: lane (kh,lr) reads x[r0+lr][28t + 8kh + j]; kh==3 upper half is
    // {1.0 (k=28 bias hook), 0,0,0} — Wx rows 29..31 are zero.
    const f32x4 onec = {1.f, 0.f, 0.f, 0.f};
    const float* xr = x + (size_t)(r0 + lr) * 784 + 8 * kh;
    f32x4 xa = *(const f32x4*)xr;
    f32x4 xc = (kh < 3) ? *(const f32x4*)(xr + 4) : onec;
    bf16x8 xb = cvt8(xa, xc);
    const f32x4 z4 = {0.f, 0.f, 0.f, 0.f};

    int cur = 0;
    for (int t = 0; t < TST; ++t) {
        f32x4 acc[2];
        // x part (bias rides in Wx row 28)
        #pragma unroll
        for (int t4 = 0; t4 < 2; ++t4)
            acc[t4] = __builtin_amdgcn_mfma_f32_16x16x32_bf16(wx[t4], xb, z4, 0, 0, 0);
        // prefetch next x under the MFMAs
        f32x4 na, nc;
        const bool pf = (t + 1 < TST);
        if (pf) {
            const float* xp = xr + (t + 1) * 28;
            na = *(const f32x4*)xp;
            nc = (kh < 3) ? *(const f32x4*)(xp + 4) : onec;
        }
        // h B-frags: 4x b128 row-reads
        bf16x8 hbv[4];
        #pragma unroll
        for (int kk = 0; kk < 4; ++kk)
            hbv[kk] = *(const bf16x8*)&Hs[cur][lr][kk * 32 + kh * 8];
        #pragma unroll
        for (int kk = 0; kk < 4; ++kk)
            #pragma unroll
            for (int t4 = 0; t4 < 2; ++t4)
                acc[t4] = __builtin_amdgcn_mfma_f32_16x16x32_bf16(w2b[kk][t4], hbv[kk], acc[t4], 0, 0, 0);
        // relu + pack -> one 8B store per t4 (n-rows 32p+16t4+4kh+0..3, batch lr)
        #pragma unroll
        for (int t4 = 0; t4 < 2; ++t4) {
            f32x4 v = acc[t4];
            v[0] = fmaxf(v[0], 0.f); v[1] = fmaxf(v[1], 0.f);
            v[2] = fmaxf(v[2], 0.f); v[3] = fmaxf(v[3], 0.f);
            unsigned lo, hi;
            asm("v_cvt_pk_bf16_f32 %0, %1, %2" : "=v"(lo) : "v"(v[0]), "v"(v[1]));
            asm("v_cvt_pk_bf16_f32 %0, %1, %2" : "=v"(hi) : "v"(v[2]), "v"(v[3]));
            u32x2 st = {lo, hi};
            *(u32x2*)&Hs[cur ^ 1][lr][p * 32 + t4 * 16 + kh * 4] = st;
        }
        if (pf) xb = cvt8(na, nc);
        __syncthreads();
        cur ^= 1;
    }

    // epilogue: p==0 wave computes out^T = W3^T.h^T + b3
    if (p == 0) {
        bf16x8 w3f[4];
        #pragma unroll
        for (int kk = 0; kk < 4; ++kk) w3f[kk] = *(const bf16x8*)(P + 40 + kk * 4);
        const float* bp = (const float*)(P + 56);
        f32x4 accO = {bp[0], bp[1], bp[2], bp[3]};
        #pragma unroll
        for (int kk = 0; kk < 4; ++kk) {
            bf16x8 hb = *(const bf16x8*)&Hs[cur][lr][kk * 32 + kh * 8];
            accO = __builtin_amdgcn_mfma_f32_16x16x32_bf16(w3f[kk], hb, accO, 0, 0, 0);
        }
        float* op = out + (size_t)(r0 + lr) * 10 + kh * 4;
        #pragma unroll
        for (int j = 0; j < 4; ++j)
            if (kh * 4 + j < 10) op[j] = accO[j];
    }
}

extern "C" void kernel_launch(void* const* d_in, const int* in_sizes, int n_in,
                              void* d_out, int out_size, void* d_ws, size_t ws_size,
                              hipStream_t stream) {
    const float* x  = (const float*)d_in[0];
    const float* W1 = (const float*)d_in[1];
    const float* b1 = (const float*)d_in[2];
    const float* W2 = (const float*)d_in[3];
    const float* b2 = (const float*)d_in[4];
    const float* W3 = (const float*)d_in[5];
    const float* b3 = (const float*)d_in[6];
    unsigned int* ws = (unsigned int*)d_ws;   // 19456 dwords = 76 KiB

    pack1<<<31, 128, 0, stream>>>(W1, b1, W2, b2, W3, b3, ws);
    pack2<<<1, 64, 0, stream>>>(ws);
    rnn_kernel<<<BTOT / 16, 256, 0, stream>>>(x, ws, (float*)d_out);
}

// Round 11
// 80.486 us; speedup vs baseline: 1.1938x; 1.1938x over previous
//
#include <hip/hip_runtime.h>

#define BTOT 65536
#define TST  28
#define PACK_DW 100
// ws layout (dwords): [0 .. 12800) packed frags (2 p-variants x 64 lanes x 100)
//                     [12800 .. 16896) WxL: 32 x 128 f32 (rows 29..31 zeroed)
#define WXL_OFF 12800

typedef __attribute__((ext_vector_type(8))) short bf16x8;
typedef __attribute__((ext_vector_type(4))) float f32x4;
typedef __attribute__((ext_vector_type(2))) unsigned int u32x2;

__device__ __forceinline__ unsigned int f2bf(float f) {
    unsigned u = __float_as_uint(f);
    u += 0x7fff + ((u >> 16) & 1);   // RNE
    return u >> 16;
}
__device__ __forceinline__ unsigned int pk2bf(float a, float b) {
    return f2bf(a) | (f2bf(b) << 16);
}
__device__ __forceinline__ bf16x8 cvt8(f32x4 a, f32x4 b) {
    union { unsigned int u[4]; bf16x8 v; } r;
    asm("v_cvt_pk_bf16_f32 %0, %1, %2" : "=v"(r.u[0]) : "v"(a[0]), "v"(a[1]));
    asm("v_cvt_pk_bf16_f32 %0, %1, %2" : "=v"(r.u[1]) : "v"(a[2]), "v"(a[3]));
    asm("v_cvt_pk_bf16_f32 %0, %1, %2" : "=v"(r.u[2]) : "v"(b[0]), "v"(b[1]));
    asm("v_cvt_pk_bf16_f32 %0, %1, %2" : "=v"(r.u[3]) : "v"(b[2]), "v"(b[3]));
    return r.v;
}

// pack1: blocks 0..28 compute WxL row k (Wx = W1@W2a; row 28 = b2 + b1@W2a, the
// bias row hit by x-frag element k=28 := 1.0; block 28 also zeroes rows 29..31).
// Block 29 packs W2b A-frags (both p-halves); block 30 packs W3 frags + b3
// (p=0 rows only — the epilogue wave).
__global__ void pack1(const float* __restrict__ W1, const float* __restrict__ b1,
                      const float* __restrict__ W2, const float* __restrict__ b2,
                      const float* __restrict__ W3, const float* __restrict__ b3,
                      unsigned int* __restrict__ ws) {
    float* WxL = (float*)(ws + WXL_OFF);
    const int bid = blockIdx.x, tid = threadIdx.x;
    if (bid < 29) {
        const int k = bid, n = tid;   // 128 threads
        float s = 0.f;
        if (k < 28) {
            for (int m = 0; m < 128; ++m) s += W1[k * 128 + m] * W2[m * 128 + n];
        } else {
            s = b2[n];
            for (int m = 0; m < 128; ++m) s += b1[m] * W2[m * 128 + n];
        }
        WxL[k * 128 + n] = s;
        if (k == 28) { WxL[29*128+n] = 0.f; WxL[30*128+n] = 0.f; WxL[31*128+n] = 0.f; }
    } else if (bid == 29) {
        if (tid < 64) {
            const int lr = tid & 15, kh = tid >> 4;
            for (int p = 0; p < 2; ++p) {
                unsigned int* P = ws + (p * 64 + tid) * PACK_DW;
                for (int kk = 0; kk < 4; ++kk)
                    for (int t = 0; t < 4; ++t)
                        for (int jd = 0; jd < 4; ++jd) {
                            const int k = 128 + kk * 32 + kh * 8 + jd * 2;
                            const int n = p * 64 + t * 16 + lr;
                            P[(kk * 4 + t) * 4 + jd] =
                                pk2bf(W2[k * 128 + n], W2[(k + 1) * 128 + n]);
                        }
            }
        }
    } else {
        if (tid < 64) {
            const int lr = tid & 15, kh = tid >> 4;
            unsigned int* P = ws + tid * PACK_DW;   // p=0 rows only
            for (int kk = 0; kk < 4; ++kk)
                for (int jd = 0; jd < 4; ++jd) {
                    const int k = kk * 32 + kh * 8 + jd * 2;
                    float lo = (lr < 10) ? W3[k * 10 + lr] : 0.f;
                    float hi = (lr < 10) ? W3[(k + 1) * 10 + lr] : 0.f;
                    P[80 + kk * 4 + jd] = pk2bf(lo, hi);
                }
            for (int j = 0; j < 4; ++j) {
                const int o = kh * 4 + j;
                P[96 + j] = __float_as_uint((o < 10) ? b3[o] : 0.f);
            }
        }
    }
}

// pack2: Wx A-frags (needs WxL from pack1's blocks 0..28).
__global__ void pack2(unsigned int* __restrict__ ws) {
    const int tid = threadIdx.x;
    if (tid < 64) {
        const float* WxL = (const float*)(ws + WXL_OFF);
        const int lr = tid & 15, kh = tid >> 4;
        for (int p = 0; p < 2; ++p) {
            unsigned int* P = ws + (p * 64 + tid) * PACK_DW;
            for (int t = 0; t < 4; ++t)
                for (int jd = 0; jd < 4; ++jd) {
                    const int k = kh * 8 + jd * 2, n = p * 64 + t * 16 + lr;
                    P[64 + t * 4 + jd] = pk2bf(WxL[k * 128 + n], WxL[(k + 1) * 128 + n]);
                }
        }
    }
}

// Round-6 structure (best: 80.4us): block = 2 teams x 2 waves; team owns 16
// batch rows; wave p owns n-half [64p,64p+64); H double-buffered, 1 barrier
// per step. NEW: H stored in B-FRAG ORDER — uint index kk*256+kh*64+lr*4+jd,
// i.e. hidden pair (kk*32+kh*8+2jd) of batch lr. Reads become lane-linear
// (base + lane*16B: zero bank conflicts); writes are <=2-way aliased (free).
__global__ __launch_bounds__(256, 3) void rnn_kernel(
    const float* __restrict__ x, const unsigned int* __restrict__ wsPack,
    float* __restrict__ out)
{
    __shared__ __align__(16) unsigned int Hs[2][2][1024];  // [team][buf][frag-order]
    const int tid = threadIdx.x;
    const int w = tid >> 6, lane = tid & 63, lr = lane & 15, kh = lane >> 4;
    const int g = w >> 1, p = w & 1;
    const int r0 = blockIdx.x * 32 + g * 16;

    const unsigned int* P = wsPack + (p * 64 + lane) * PACK_DW;
    bf16x8 w2b[4][4], wx[4];
    #pragma unroll
    for (int kk = 0; kk < 4; ++kk)
        #pragma unroll
        for (int t = 0; t < 4; ++t)
            w2b[kk][t] = *(const bf16x8*)(P + (kk * 4 + t) * 4);
    #pragma unroll
    for (int t = 0; t < 4; ++t) wx[t] = *(const bf16x8*)(P + 64 + t * 4);

    // write-address constants per (p, t4, kh): hidden base q0 = p*64+t4*16+kh*4
    //   kkW = p*2 + (t4>>1); khR = (t4*2 + (kh>>1)) & 3; jd = 2*(kh&1)
    unsigned wAddr[4];
    #pragma unroll
    for (int t4 = 0; t4 < 4; ++t4) {
        const int kkW = p * 2 + (t4 >> 1);
        const int khR = (t4 * 2 + (kh >> 1)) & 3;
        const int jd  = (kh & 1) * 2;
        wAddr[t4] = kkW * 256 + khR * 64 + lr * 4 + jd;
    }

    // zero buf0 of both teams (2 x 1024 uints)
    #pragma unroll
    for (int i = 0; i < 4; ++i) {
        Hs[0][0][tid + i * 256] = 0u;
        Hs[1][0][tid + i * 256] = 0u;
    }
    __syncthreads();

    // x B-frag: lane (kh,lr) reads x[r0+lr][28t + 8kh + j]; kh==3 upper half is
    // {1.0 (k=28 bias hook), 0,0,0} — Wx rows 29..31 are zero.
    const f32x4 onec = {1.f, 0.f, 0.f, 0.f};
    const float* xr = x + (size_t)(r0 + lr) * 784 + 8 * kh;
    f32x4 xa = *(const f32x4*)xr;
    f32x4 xc = (kh < 3) ? *(const f32x4*)(xr + 4) : onec;
    bf16x8 xb = cvt8(xa, xc);
    const f32x4 z4 = {0.f, 0.f, 0.f, 0.f};

    int cur = 0;
    for (int t = 0; t < TST; ++t) {
        f32x4 acc[4];
        // x part (bias rides in Wx row 28)
        #pragma unroll
        for (int t4 = 0; t4 < 4; ++t4)
            acc[t4] = __builtin_amdgcn_mfma_f32_16x16x32_bf16(wx[t4], xb, z4, 0, 0, 0);
        // prefetch next x under the MFMAs
        f32x4 na, nc;
        const bool pf = (t + 1 < TST);
        if (pf) {
            const float* xp = xr + (t + 1) * 28;
            na = *(const f32x4*)xp;
            nc = (kh < 3) ? *(const f32x4*)(xp + 4) : onec;
        }
        // h B-frags: lane-linear b128 reads (zero conflicts)
        bf16x8 hbv[4];
        #pragma unroll
        for (int kk = 0; kk < 4; ++kk)
            hbv[kk] = *(const bf16x8*)&Hs[g][cur][kk * 256 + lane * 4];
        #pragma unroll
        for (int kk = 0; kk < 4; ++kk)
            #pragma unroll
            for (int t4 = 0; t4 < 4; ++t4)
                acc[t4] = __builtin_amdgcn_mfma_f32_16x16x32_bf16(w2b[kk][t4], hbv[kk], acc[t4], 0, 0, 0);
        // relu + pack -> one b64 store per t4 into frag-order slots (<=2-way)
        #pragma unroll
        for (int t4 = 0; t4 < 4; ++t4) {
            f32x4 v = acc[t4];
            v[0] = fmaxf(v[0], 0.f); v[1] = fmaxf(v[1], 0.f);
            v[2] = fmaxf(v[2], 0.f); v[3] = fmaxf(v[3], 0.f);
            unsigned lo, hi;
            asm("v_cvt_pk_bf16_f32 %0, %1, %2" : "=v"(lo) : "v"(v[0]), "v"(v[1]));
            asm("v_cvt_pk_bf16_f32 %0, %1, %2" : "=v"(hi) : "v"(v[2]), "v"(v[3]));
            u32x2 st = {lo, hi};
            *(u32x2*)&Hs[g][cur ^ 1][wAddr[t4]] = st;
        }
        if (pf) xb = cvt8(na, nc);
        __syncthreads();
        cur ^= 1;
    }

    // epilogue: p==0 wave of each team computes out^T = W3^T.h^T + b3
    if (p == 0) {
        bf16x8 w3f[4];
        #pragma unroll
        for (int kk = 0; kk < 4; ++kk) w3f[kk] = *(const bf16x8*)(P + 80 + kk * 4);
        const float* bp = (const float*)(P + 96);
        f32x4 accO = {bp[0], bp[1], bp[2], bp[3]};
        #pragma unroll
        for (int kk = 0; kk < 4; ++kk) {
            bf16x8 hb = *(const bf16x8*)&Hs[g][cur][kk * 256 + lane * 4];
            accO = __builtin_amdgcn_mfma_f32_16x16x32_bf16(w3f[kk], hb, accO, 0, 0, 0);
        }
        float* op = out + (size_t)(r0 + lr) * 10 + kh * 4;
        #pragma unroll
        for (int j = 0; j < 4; ++j)
            if (kh * 4 + j < 10) op[j] = accO[j];
    }
}

extern "C" void kernel_launch(void* const* d_in, const int* in_sizes, int n_in,
                              void* d_out, int out_size, void* d_ws, size_t ws_size,
                              hipStream_t stream) {
    const float* x  = (const float*)d_in[0];
    const float* W1 = (const float*)d_in[1];
    const float* b1 = (const float*)d_in[2];
    const float* W2 = (const float*)d_in[3];
    const float* b2 = (const float*)d_in[4];
    const float* W3 = (const float*)d_in[5];
    const float* b3 = (const float*)d_in[6];
    unsigned int* ws = (unsigned int*)d_ws;   // 16896 dwords = 66 KiB

    pack1<<<31, 128, 0, stream>>>(W1, b1, W2, b2, W3, b3, ws);
    pack2<<<1, 64, 0, stream>>>(ws);
    rnn_kernel<<<BTOT / 32, 256, 0, stream>>>(x, ws, (float*)d_out);
}